// Round 11
// baseline (1244.724 us; speedup 1.0000x reference)
//
#include <hip/hip_runtime.h>

#define NTOK 49
#define CDIM 192
#define NHEAD 6
#define HDIM 32

typedef float f32x4 __attribute__((ext_vector_type(4), may_alias));
typedef float f32x4u __attribute__((ext_vector_type(4), may_alias, aligned(4)));
typedef short b16x8 __attribute__((ext_vector_type(8), may_alias));
typedef short b16x4 __attribute__((ext_vector_type(4), may_alias));

__device__ __forceinline__ f32x4 MFMA(b16x8 a, b16x8 b, f32x4 c) {
  return __builtin_amdgcn_mfma_f32_16x16x32_bf16(a, b, c, 0, 0, 0);
}

// Bit-twiddle RNE f32->bf16 (R2-R9 verified, zero-spill codegen).
// NOTE (R10 post-mortem): the native __bf16 cast caused a 1.5 GB scratch
// spill storm (scalarized vector construction) — do NOT use it here.
__device__ __forceinline__ short f2bf(float f) {
  unsigned u = __builtin_bit_cast(unsigned, f);
  u += 0x7FFFu + ((u >> 16) & 1u);
  return (short)(u >> 16);
}

// XOR swizzles (granule 8 shorts = 16B), bijective per row. All verified R5-R9.
__device__ __forceinline__ int swz(int r, int c) {   // [64][192]
  return r * 192 + (c ^ ((r & 7) << 3));
}
__device__ __forceinline__ int swz64(int r, int c) { // [192][64] (row=chan)
  return r * 64 + (c ^ ((r & 7) << 3));
}
__device__ __forceinline__ int ps(int r, int c) {    // [16][32] P scratch
  return r * 32 + (c ^ ((((r & 3) ^ ((r >> 2) & 3)) & 3) << 3));
}

// ---- prep 1: fp32 weights -> bf16 ws. Wq pre-scaled by D^-0.5 ----
__global__ void prep_w(const float* __restrict__ Wq, const float* __restrict__ Wkv,
                       const float* __restrict__ Wo, short* __restrict__ wsW) {
  const float scale = 0.17677669529663687f;
  int i = blockIdx.x * 256 + threadIdx.x;
  if (i >= 147456) return;
  float v;
  if (i < 36864)        v = Wq[i] * scale;
  else if (i < 110592)  v = Wkv[i - 36864];
  else                  v = Wo[i - 110592];
  wsW[i] = f2bf(v);
}

// ---- prep 2: rel-pos-bias [6][49][64] f32; k-pad (49..63) = -1e9 mask ----
__global__ void prep_bias(const float* __restrict__ rpb, float* __restrict__ bias_t) {
  int idx = blockIdx.x * 256 + threadIdx.x;
  if (idx >= NHEAD * NTOK * 64) return;
  int k = idx & 63;
  int q = (idx >> 6) % NTOK;
  int h = idx / (NTOK * 64);
  float v = -1e9f;
  if (k < NTOK) {
    int ci = (q / 7) * 13 + (q % 7);
    int jj = 48 - k;
    int cj = (jj / 7) * 13 + (jj % 7);
    v = rpb[(ci + cj) * NHEAD + h];
  }
  bias_t[idx] = v;
}

// Fused window-MSA, minimal-barrier edition: 1 window/block, 8 waves, 7 barriers.
// LDS (shorts): X [0,12288) | KH [12288,24576) | VT [24576,36864)  (73728 B).
// Residency is wave-capped (~15 waves/CU at VGPR~64), NOT LDS-capped.
// X: per-wave qh scratch -> kv stage -> per-wave P scratch -> x.
// Swapped QK^T (lane owns q-row, in-lane softmax, 2 shuffles). Epilogue: f32
// bounce overlaid on KH+VT, single pass, coalesced stores.
__global__ __launch_bounds__(512, 4) void wmsa_kernel(
    const float* __restrict__ qg, const float* __restrict__ kvg,
    const float* __restrict__ maskg, const float* __restrict__ bq,
    const float* __restrict__ bkv, const float* __restrict__ bo,
    const short* __restrict__ wsW, const float* __restrict__ bias_t,
    float* __restrict__ outg, int nW) {
  __shared__ short lds[36864];      // 73728 B
  short* X = lds;
  short* KH = lds + 12288;
  short* VT = lds + 24576;
  float* BF = (float*)(lds + 12288);  // epilogue [49][196] f32 = 38416 B <= 49152

  const int b = blockIdx.x;
  const int tid = threadIdx.x;
  const int w = tid >> 6;
  const int lane = tid & 63;
  const int l15 = lane & 15;
  const int lg = lane >> 4;
  const int R = w >> 1, hw = w & 1;
  const f32x4 zero4 = {0.f, 0.f, 0.f, 0.f};

  const short* WqB = wsW;
  const short* WkvB = wsW + 36864;
  const short* WoB = wsW + 110592;

  const float* qsrc = qg + (size_t)b * (NTOK * CDIM);
  const float* kvsrc = kvg + (size_t)b * (NTOK * CDIM);
  const float* maskw = maskg + (size_t)(b % nW) * (NTOK * NTOK);

  const int qrow = R * 16 + l15;
  const int qc = qrow > 48 ? 48 : qrow;  // pad lanes -> row 48 (outputs unused)

  // ============ 1. q-projection (per-wave; verified R8/R9) ============
  b16x8 aq6[6];
#pragma unroll
  for (int kk = 0; kk < 6; ++kk) {
    f32x4 lo = *(const f32x4*)(qsrc + qc * CDIM + kk * 32 + lg * 8);
    f32x4 hi = *(const f32x4*)(qsrc + qc * CDIM + kk * 32 + lg * 8 + 4);
    b16x8 a = {f2bf(lo[0]), f2bf(lo[1]), f2bf(lo[2]), f2bf(lo[3]),
               f2bf(hi[0]), f2bf(hi[1]), f2bf(hi[2]), f2bf(hi[3])};
    aq6[kk] = a;
  }
#pragma unroll
  for (int t = 0; t < 6; ++t) {
    const int col = (2 * (t >> 1) + hw) * 32 + (t & 1) * 16 + l15;
    f32x4 acc = zero4;
#pragma unroll
    for (int kk = 0; kk < 6; ++kk) {
      b16x8 bw = *(const b16x8*)(WqB + col * CDIM + kk * 32 + lg * 8);
      acc = MFMA(aq6[kk], bw, acc);
    }
    const float bias = bq[col] * 0.17677669529663687f;
#pragma unroll
    for (int rr = 0; rr < 4; ++rr)
      X[swz(R * 16 + lg * 4 + rr, hw * 96 + t * 16 + l15)] = f2bf(acc[rr] + bias);
  }
  b16x8 aq[3];
#pragma unroll
  for (int p = 0; p < 3; ++p)
    aq[p] = *(const b16x8*)(X + swz(R * 16 + l15, hw * 96 + p * 32 + lg * 8));
  __syncthreads();  // B1

  // ============ 2. stage kv -> X (bf16, rows>=49 zero) ============
#pragma unroll
  for (int it = 0; it < 6; ++it) {
    int idx = tid + it * 512;
    int r = idx / 48, c4 = idx % 48;
    f32x4 v = (r < NTOK) ? *(const f32x4*)(kvsrc + r * CDIM + c4 * 4) : zero4;
    b16x4 o = {f2bf(v[0]), f2bf(v[1]), f2bf(v[2]), f2bf(v[3])};
    *(b16x4*)(X + swz(r, c4 * 4)) = o;
  }
  __syncthreads();  // B2

  // ============ 3. kv-projection, one parallel phase (verified R5) ============
  // wave w -> col-tiles w*3+{0,1,2} of 24 (cols 0..383)
#pragma unroll
  for (int jj = 0; jj < 3; ++jj) {
    const int nt = w * 3 + jj;
    const int col = nt * 16 + l15;
    f32x4 acc[4];
#pragma unroll
    for (int m = 0; m < 4; ++m) acc[m] = zero4;
#pragma unroll
    for (int kk = 0; kk < 6; ++kk) {
      b16x8 bw = *(const b16x8*)(WkvB + col * CDIM + kk * 32 + lg * 8);
#pragma unroll
      for (int m = 0; m < 4; ++m) {
        b16x8 a = *(const b16x8*)(X + swz(m * 16 + l15, kk * 32 + lg * 8));
        acc[m] = MFMA(a, bw, acc[m]);
      }
    }
    const float bias = bkv[col];
    if (col < CDIM) {  // K -> KH[token][chan]
#pragma unroll
      for (int m = 0; m < 4; ++m)
#pragma unroll
        for (int rr = 0; rr < 4; ++rr)
          KH[swz(m * 16 + lg * 4 + rr, col)] = f2bf(acc[m][rr] + bias);
    } else {  // V -> VT[chan][token]
      const int c = col - CDIM;
#pragma unroll
      for (int m = 0; m < 4; ++m) {
        b16x4 o = {f2bf(acc[m][0] + bias), f2bf(acc[m][1] + bias),
                   f2bf(acc[m][2] + bias), f2bf(acc[m][3] + bias)};
        *(b16x4*)(VT + swz64(c, m * 16 + lg * 4)) = o;
      }
    }
  }
  __syncthreads();  // B3: kh/vT ready; X(kv) dead -> P scratch

  // ============ 4. pair loop: ZERO barriers (verified R8 mechanics) ============
  b16x8 xbf[3];
#pragma unroll
  for (int p = 0; p < 3; ++p) {
    const int h = 2 * p + hw;
    f32x4 Ls[4];
#pragma unroll
    for (int nt = 0; nt < 4; ++nt) {
      b16x8 bk = *(const b16x8*)(KH + swz(nt * 16 + l15, h * HDIM + lg * 8));
      Ls[nt] = MFMA(bk, aq[p], zero4);
    }
    const float* bt = bias_t + (h * NTOK + qc) * 64;
#pragma unroll
    for (int nt = 0; nt < 4; ++nt) {
      f32x4 bb = *(const f32x4*)(bt + nt * 16 + lg * 4);
#pragma unroll
      for (int rr = 0; rr < 4; ++rr) Ls[nt][rr] += bb[rr];
    }
#pragma unroll
    for (int nt = 0; nt < 3; ++nt) {
      f32x4 mm = *(const f32x4u*)(maskw + qc * NTOK + nt * 16 + lg * 4);
#pragma unroll
      for (int rr = 0; rr < 4; ++rr) Ls[nt][rr] += mm[rr];
    }
    if (lg == 0) Ls[3][0] += maskw[qc * NTOK + 48];

    float mx = Ls[0][0];
#pragma unroll
    for (int nt = 0; nt < 4; ++nt)
#pragma unroll
      for (int rr = 0; rr < 4; ++rr) mx = fmaxf(mx, Ls[nt][rr]);
    mx = fmaxf(mx, __shfl_xor(mx, 16));
    mx = fmaxf(mx, __shfl_xor(mx, 32));
    float sum = 0.f;
#pragma unroll
    for (int nt = 0; nt < 4; ++nt)
#pragma unroll
      for (int rr = 0; rr < 4; ++rr) {
        Ls[nt][rr] = __expf(Ls[nt][rr] - mx);
        sum += Ls[nt][rr];
      }
    sum += __shfl_xor(sum, 16);
    sum += __shfl_xor(sum, 32);
    const float inv = 1.f / sum;

    short* Pscr = X + w * 512;  // per-wave [16][32] in dead kv region
    b16x8 ap[2];
#pragma unroll
    for (int kkh = 0; kkh < 2; ++kkh) {
#pragma unroll
      for (int nth = 0; nth < 2; ++nth) {
        const int nt = 2 * kkh + nth;
        b16x4 o = {f2bf(Ls[nt][0] * inv), f2bf(Ls[nt][1] * inv),
                   f2bf(Ls[nt][2] * inv), f2bf(Ls[nt][3] * inv)};
        *(b16x4*)(Pscr + ps(l15, nth * 16 + lg * 4)) = o;
      }
      ap[kkh] = *(const b16x8*)(Pscr + ps(l15, lg * 8));
    }
    f32x4 xa[2] = {zero4, zero4};
#pragma unroll
    for (int kkh = 0; kkh < 2; ++kkh)
#pragma unroll
      for (int nv = 0; nv < 2; ++nv) {
        b16x8 bv = *(const b16x8*)(VT + swz64(h * HDIM + nv * 16 + l15,
                                              kkh * 32 + lg * 8));
        xa[nv] = MFMA(ap[kkh], bv, xa[nv]);
      }
    b16x8 xb = {f2bf(xa[0][0]), f2bf(xa[0][1]), f2bf(xa[0][2]), f2bf(xa[0][3]),
                f2bf(xa[1][0]), f2bf(xa[1][1]), f2bf(xa[1][2]), f2bf(xa[1][3])};
    xbf[p] = xb;
  }
  __syncthreads();  // B4: all P-scratch reads done -> X writable as x

  // ============ 5. x -> X ============
#pragma unroll
  for (int p = 0; p < 3; ++p) {
    const int h = 2 * p + hw;
#pragma unroll
    for (int nv = 0; nv < 2; ++nv)
#pragma unroll
      for (int rr = 0; rr < 4; ++rr)
        X[swz(R * 16 + lg * 4 + rr, h * HDIM + nv * 16 + l15)] = xbf[p][nv * 4 + rr];
  }
  __syncthreads();  // B5: x ready

  // ============ 6. output projection ============
  f32x4 oacc[6];
#pragma unroll
  for (int t = 0; t < 6; ++t) oacc[t] = zero4;
#pragma unroll
  for (int t = 0; t < 6; ++t) {
    const int j = 2 * t + (w >> 2);
    const int m = w & 3;
    const int col = j * 16 + l15;
#pragma unroll
    for (int kk = 0; kk < 6; ++kk) {
      b16x8 a = *(const b16x8*)(X + swz(m * 16 + l15, kk * 32 + lg * 8));
      b16x8 bw = *(const b16x8*)(WoB + col * CDIM + kk * 32 + lg * 8);
      oacc[t] = MFMA(a, bw, oacc[t]);
    }
  }
  __syncthreads();  // B6: KH/VT dead -> BF overlay writable

  // ---- single-pass f32 bounce [49][196] in KH+VT region ----
  {
    const int m = w & 3;
#pragma unroll
    for (int t = 0; t < 6; ++t) {
      const int col = (2 * t + (w >> 2)) * 16 + l15;
      const float bias = bo[col];
#pragma unroll
      for (int rr = 0; rr < 4; ++rr) {
        const int row = m * 16 + lg * 4 + rr;
        if (row < NTOK) BF[row * 196 + col] = oacc[t][rr] + bias;
      }
    }
  }
  __syncthreads();  // B7

  float* dst = outg + (size_t)b * (NTOK * CDIM);
#pragma unroll
  for (int it = 0; it < 5; ++it) {
    int idx = tid + it * 512;
    if (idx < NTOK * 48) {
      int row = idx / 48, c4 = idx % 48;
      *(f32x4*)(dst + row * CDIM + c4 * 4) = *(const f32x4*)(BF + row * 196 + c4 * 4);
    }
  }
}

extern "C" void kernel_launch(void* const* d_in, const int* in_sizes, int n_in,
                              void* d_out, int out_size, void* d_ws, size_t ws_size,
                              hipStream_t stream) {
  const float* q = (const float*)d_in[0];
  const float* kv = (const float*)d_in[1];
  const float* mask = (const float*)d_in[2];
  const float* Wq = (const float*)d_in[3];
  const float* bq = (const float*)d_in[4];
  const float* Wkv = (const float*)d_in[5];
  const float* bkv = (const float*)d_in[6];
  const float* Wo = (const float*)d_in[7];
  const float* bo = (const float*)d_in[8];
  const float* rpb = (const float*)d_in[9];
  short* wsW = (short*)d_ws;
  float* bias_t = (float*)((char*)d_ws + 294912);  // [6][49][64] f32, 75264 B

  const int B = in_sizes[0] / (NTOK * CDIM);
  const int nW = in_sizes[2] / (NTOK * NTOK);

  prep_w<<<576, 256, 0, stream>>>(Wq, Wkv, Wo, wsW);
  prep_bias<<<(NHEAD * NTOK * 64 + 255) / 256, 256, 0, stream>>>(rpb, bias_t);
  wmsa_kernel<<<B, 512, 0, stream>>>(q, kv, mask, bq, bkv, bo, wsW, bias_t,
                                     (float*)d_out, nW);
}

// Round 12
// 889.738 us; speedup vs baseline: 1.3990x; 1.3990x over previous
//
#include <hip/hip_runtime.h>

#define NTOK 49
#define CDIM 192
#define NHEAD 6
#define HDIM 32

typedef float f32x4 __attribute__((ext_vector_type(4), may_alias));
typedef short b16x8 __attribute__((ext_vector_type(8), may_alias));
typedef short b16x4 __attribute__((ext_vector_type(4), may_alias));

__device__ __forceinline__ f32x4 MFMA(b16x8 a, b16x8 b, f32x4 c) {
  return __builtin_amdgcn_mfma_f32_16x16x32_bf16(a, b, c, 0, 0, 0);
}

__device__ __forceinline__ short f2bf(float f) {
  unsigned u = __builtin_bit_cast(unsigned, f);
  u += 0x7FFFu + ((u >> 16) & 1u);  // round-to-nearest-even
  return (short)(u >> 16);
}

// XOR swizzle for [64][192] bf16 tiles: 8-short (16B) granules, bijective
// within each 8-row stripe; makes 16-row-column b128 reads 2-way (free).
__device__ __forceinline__ int swz(int row, int col) {
  return row * CDIM + (col ^ ((row & 7) << 3));
}

// ---- prep 1: fp32 weights -> bf16 ws. Wq pre-scaled by D^-0.5 ----
// ws shorts: [0,36864) Wq | [36864,110592) Wkv | [110592,147456) Wo
__global__ void prep_w(const float* __restrict__ Wq, const float* __restrict__ Wkv,
                       const float* __restrict__ Wo, short* __restrict__ wsW) {
  const float scale = 0.17677669529663687f;
  int i = blockIdx.x * 256 + threadIdx.x;
  if (i >= 147456) return;
  float v;
  if (i < 36864)        v = Wq[i] * scale;
  else if (i < 110592)  v = Wkv[i - 36864];
  else                  v = Wo[i - 110592];
  wsW[i] = f2bf(v);
}

// ---- prep 2: rel-pos-bias table [H][49][49] f32 (57.6 KB, stays L2-hot) ----
__global__ void prep_bias(const float* __restrict__ rpb, float* __restrict__ bias_t) {
  int idx = blockIdx.x * 256 + threadIdx.x;
  if (idx >= NHEAD * NTOK * NTOK) return;
  int h = idx / (NTOK * NTOK);
  int p = idx % (NTOK * NTOK);
  int i = p / NTOK, j = p % NTOK;
  int ci = (i / 7) * 13 + (i % 7);
  int jj = 48 - j;
  int cj = (jj / 7) * 13 + (jj % 7);
  bias_t[idx] = rpb[(ci + cj) * NHEAD + h];
}

// Fused window-MSA (R5 champion structure, zero-spill verified at 894 us).
// SINGLE CHANGE vs champion: waves_per_eu 4 -> 3 (total-reg cap 128 -> ~170):
// trade 16->12 waves/CU of TLP for deeper per-wave load pipelining (ILP).
// Phase order: stage q -> q-proj (per-wave own tile) -> stage kv (regs held
// only during q-proj) -> kv-proj -> attention -> o-proj.
// LDS (shorts): SH [0,12288) | VT [12288,25344) | KH [25344,37632).
// SH: q-stage -> per-wave qh -> kv-stage -> per-wave P -> (w/ VT) f32 bounce.
// KH: kh -> x.  VT: vhT.
__global__ __attribute__((amdgpu_flat_work_group_size(512, 512),
                          amdgpu_waves_per_eu(3))) void wmsa_kernel(
    const float* __restrict__ qg, const float* __restrict__ kvg,
    const float* __restrict__ maskg, const float* __restrict__ bq,
    const float* __restrict__ bkv, const float* __restrict__ bo,
    const short* __restrict__ wsW, const float* __restrict__ bias_t,
    float* __restrict__ outg, int nW) {
  __shared__ short lds[37632];     // 75264 B
  short* SH = lds;                 // [64][192] swizzled
  short* VT = lds + 12288;         // [192][68] vhT[c][token]
  short* KH = lds + 25344;         // [64][192] swizzled
  float* BF = (float*)lds;         // epilogue bounce [49][204] f32 (40 KB)

  const int b = blockIdx.x;
  const int tid = threadIdx.x;
  const int w = tid >> 6;          // wave 0..7
  const int lane = tid & 63;
  const int l15 = lane & 15;
  const int lg = lane >> 4;
  const int R = w >> 1, hw = w & 1, h0 = hw * 3;
  const float scale = 0.17677669529663687f;
  const f32x4 zero4 = {0.f, 0.f, 0.f, 0.f};

  const short* WqB = wsW;
  const short* WkvB = wsW + 36864;
  const short* WoB = wsW + 110592;

  const float* qsrc = qg + (size_t)b * (NTOK * CDIM);
  const float* kvsrc = kvg + (size_t)b * (NTOK * CDIM);

  // ---- issue q and kv loads up front (HBM latency hidden under staging+q-proj) ----
  f32x4 qv[6], kvreg[6];
#pragma unroll
  for (int it = 0; it < 6; ++it) {
    int idx = tid + it * 512;
    int r = idx / 48, c4 = idx % 48;
    qv[it] = (r < NTOK) ? *(const f32x4*)(qsrc + r * CDIM + c4 * 4) : zero4;
  }
#pragma unroll
  for (int it = 0; it < 6; ++it) {
    int idx = tid + it * 512;
    int r = idx / 48, c4 = idx % 48;
    kvreg[it] = (r < NTOK) ? *(const f32x4*)(kvsrc + r * CDIM + c4 * 4) : zero4;
  }
  // ---- stage q -> SH bf16 (rows 49..63 zero) ----
#pragma unroll
  for (int it = 0; it < 6; ++it) {
    int idx = tid + it * 512;
    int r = idx / 48, c4 = idx % 48;
    b16x4 o = {f2bf(qv[it][0]), f2bf(qv[it][1]), f2bf(qv[it][2]), f2bf(qv[it][3])};
    *(b16x4*)(SH + swz(r, c4 * 4)) = o;
  }
  __syncthreads();  // B1: q staged

  // ---- q projection: wave computes exactly its own attention q-tile ----
  // rows m=R (16 rows), col-tiles j = hw*6 + t (96 cols = heads h0..h0+2)
  f32x4 qacc[6];
#pragma unroll
  for (int t = 0; t < 6; ++t) qacc[t] = zero4;
  {
    b16x8 aq6[6];
#pragma unroll
    for (int kk = 0; kk < 6; ++kk)
      aq6[kk] = *(const b16x8*)(SH + swz(R * 16 + l15, kk * 32 + lg * 8));
#pragma unroll
    for (int t = 0; t < 6; ++t) {
      const int col = (hw * 6 + t) * 16 + l15;
#pragma unroll
      for (int kk = 0; kk < 6; ++kk) {
        b16x8 bw = *(const b16x8*)(WqB + col * CDIM + kk * 32 + lg * 8);
        qacc[t] = MFMA(aq6[kk], bw, qacc[t]);
      }
    }
  }
  __syncthreads();  // B2: all q reads from SH done

  // ---- qh -> own SH region (rows R*16..+15, cols hw*96..+95), read aq ----
#pragma unroll
  for (int t = 0; t < 6; ++t) {
    const int col = (hw * 6 + t) * 16 + l15;
    const float bias = bq[col] * scale;
#pragma unroll
    for (int r = 0; r < 4; ++r)
      SH[swz(R * 16 + lg * 4 + r, hw * 96 + t * 16 + l15)] = f2bf(qacc[t][r] + bias);
  }
  b16x8 aq[3];
#pragma unroll
  for (int hh = 0; hh < 3; ++hh)
    aq[hh] = *(const b16x8*)(SH + swz(R * 16 + l15, hw * 96 + hh * 32 + lg * 8));
  __syncthreads();  // B3: qh reads done everywhere

  // ---- stage kv (from regs) -> SH ----
#pragma unroll
  for (int it = 0; it < 6; ++it) {
    int idx = tid + it * 512;
    int r = idx / 48, c4 = idx % 48;
    b16x4 o = {f2bf(kvreg[it][0]), f2bf(kvreg[it][1]), f2bf(kvreg[it][2]),
               f2bf(kvreg[it][3])};
    *(b16x4*)(SH + swz(r, c4 * 4)) = o;
  }
  __syncthreads();  // B4: kv staged

  // ---- kv projection: 24 col-tiles, wave w -> nt = w*3 + {0,1,2} ----
#pragma unroll
  for (int jj = 0; jj < 3; ++jj) {
    const int nt = w * 3 + jj;
    const int col = nt * 16 + l15;  // 0..383
    f32x4 acc[4];
#pragma unroll
    for (int m = 0; m < 4; ++m) acc[m] = zero4;
#pragma unroll
    for (int kk = 0; kk < 6; ++kk) {
      b16x8 bw = *(const b16x8*)(WkvB + col * CDIM + kk * 32 + lg * 8);
#pragma unroll
      for (int m = 0; m < 4; ++m) {
        b16x8 a = *(const b16x8*)(SH + swz(m * 16 + l15, kk * 32 + lg * 8));
        acc[m] = MFMA(a, bw, acc[m]);
      }
    }
    const float bias = bkv[col];
    if (col < CDIM) {  // K half -> KH[token][col]
#pragma unroll
      for (int m = 0; m < 4; ++m)
#pragma unroll
        for (int r = 0; r < 4; ++r)
          KH[swz(m * 16 + lg * 4 + r, col)] = f2bf(acc[m][r] + bias);
    } else {  // V half -> VT[c][token]
      const int c = col - CDIM;
#pragma unroll
      for (int m = 0; m < 4; ++m) {
        b16x4 o = {f2bf(acc[m][0] + bias), f2bf(acc[m][1] + bias),
                   f2bf(acc[m][2] + bias), f2bf(acc[m][3] + bias)};
        *(b16x4*)(VT + c * 68 + m * 16 + lg * 4) = o;
      }
    }
  }
  __syncthreads();  // B5: kh/vT ready; SH kv dead

  // ---- attention: wave w -> rows R*16..+15, heads h0..h0+2 ----
  const float* maskw = maskg + (size_t)(b % nW) * (NTOK * NTOK);
  float maskv[4][4];
#pragma unroll
  for (int nt = 0; nt < 4; ++nt) {
    const int cgl = nt * 16 + l15;
#pragma unroll
    for (int r = 0; r < 4; ++r) {
      const int rw = R * 16 + lg * 4 + r;
      maskv[nt][r] = (rw < NTOK && cgl < NTOK) ? maskw[rw * NTOK + cgl] : 0.f;
    }
  }

  f32x4 xh[3][2];
#pragma unroll
  for (int hh = 0; hh < 3; ++hh) {
    xh[hh][0] = zero4;
    xh[hh][1] = zero4;
  }
#pragma unroll
  for (int hh = 0; hh < 3; ++hh) {
    const int h = h0 + hh;
    f32x4 L[4];
#pragma unroll
    for (int nt = 0; nt < 4; ++nt) {
      b16x8 bk = *(const b16x8*)(KH + swz(nt * 16 + l15, h * 32 + lg * 8));
      L[nt] = MFMA(aq[hh], bk, zero4);
    }
    const float* bt = bias_t + h * (NTOK * NTOK);
#pragma unroll
    for (int nt = 0; nt < 4; ++nt) {
      const int cgl = nt * 16 + l15;
#pragma unroll
      for (int r = 0; r < 4; ++r) {
        const int rw = R * 16 + lg * 4 + r;
        if (rw < NTOK && cgl < NTOK) L[nt][r] += bt[rw * NTOK + cgl] + maskv[nt][r];
        else                          L[nt][r] = -1e9f;
      }
    }
#pragma unroll
    for (int r = 0; r < 4; ++r) {
      float m = fmaxf(fmaxf(L[0][r], L[1][r]), fmaxf(L[2][r], L[3][r]));
      m = fmaxf(m, __shfl_xor(m, 1));
      m = fmaxf(m, __shfl_xor(m, 2));
      m = fmaxf(m, __shfl_xor(m, 4));
      m = fmaxf(m, __shfl_xor(m, 8));
      float p0 = __expf(L[0][r] - m), p1 = __expf(L[1][r] - m);
      float p2 = __expf(L[2][r] - m), p3 = __expf(L[3][r] - m);
      float s = p0 + p1 + p2 + p3;
      s += __shfl_xor(s, 1);
      s += __shfl_xor(s, 2);
      s += __shfl_xor(s, 4);
      s += __shfl_xor(s, 8);
      const float is = 1.0f / s;
      L[0][r] = p0 * is; L[1][r] = p1 * is; L[2][r] = p2 * is; L[3][r] = p3 * is;
    }
    // P -> SH own region (rows R*16..+15, cols hw*96..+63), then PV
#pragma unroll
    for (int nt = 0; nt < 4; ++nt)
#pragma unroll
      for (int r = 0; r < 4; ++r)
        SH[swz(R * 16 + lg * 4 + r, hw * 96 + nt * 16 + l15)] = f2bf(L[nt][r]);
#pragma unroll
    for (int kk = 0; kk < 2; ++kk) {
      b16x8 ap = *(const b16x8*)(SH + swz(R * 16 + l15, hw * 96 + kk * 32 + lg * 8));
#pragma unroll
      for (int nv = 0; nv < 2; ++nv) {
        b16x8 bv = *(const b16x8*)(VT + (h * 32 + nv * 16 + l15) * 68 + kk * 32 + lg * 8);
        xh[hh][nv] = MFMA(ap, bv, xh[hh][nv]);
      }
    }
  }
  __syncthreads();  // B6: all KH (kh) reads done
  // ---- x -> KH ----
#pragma unroll
  for (int hh = 0; hh < 3; ++hh)
#pragma unroll
    for (int nv = 0; nv < 2; ++nv)
#pragma unroll
      for (int r = 0; r < 4; ++r)
        KH[swz(R * 16 + lg * 4 + r, (h0 + hh) * 32 + nv * 16 + l15)] =
            f2bf(xh[hh][nv][r]);
  __syncthreads();  // B7: x ready (SH, VT dead -> bounce region)

  // ---- output projection -> f32 bounce (stride 204) ----
#pragma unroll
  for (int t = 0; t < 6; ++t) {
    const int pid = w * 6 + t;
    const int j = pid >> 2, m = pid & 3;
    const int col = j * 16 + l15;
    f32x4 oacc = zero4;
#pragma unroll
    for (int kk = 0; kk < 6; ++kk) {
      b16x8 a = *(const b16x8*)(KH + swz(m * 16 + l15, kk * 32 + lg * 8));
      b16x8 bw = *(const b16x8*)(WoB + col * CDIM + kk * 32 + lg * 8);
      oacc = MFMA(a, bw, oacc);
    }
    const float bias = bo[col];
#pragma unroll
    for (int r = 0; r < 4; ++r) {
      const int row = m * 16 + lg * 4 + r;
      if (row < NTOK) BF[row * 204 + col] = oacc[r] + bias;
    }
  }
  __syncthreads();  // B8: bounce ready

  // ---- fully coalesced output stores (16B/lane contiguous) ----
  float* dst = outg + (size_t)b * (NTOK * CDIM);
#pragma unroll
  for (int t = 0; t < 5; ++t) {
    int idx = tid + t * 512;
    if (idx < NTOK * 48) {
      int row = idx / 48, c4 = idx % 48;
      f32x4 v = *(const f32x4*)(BF + row * 204 + c4 * 4);
      *(f32x4*)(dst + row * CDIM + c4 * 4) = v;
    }
  }
}

extern "C" void kernel_launch(void* const* d_in, const int* in_sizes, int n_in,
                              void* d_out, int out_size, void* d_ws, size_t ws_size,
                              hipStream_t stream) {
  const float* q = (const float*)d_in[0];
  const float* kv = (const float*)d_in[1];
  const float* mask = (const float*)d_in[2];
  const float* Wq = (const float*)d_in[3];
  const float* bq = (const float*)d_in[4];
  const float* Wkv = (const float*)d_in[5];
  const float* bkv = (const float*)d_in[6];
  const float* Wo = (const float*)d_in[7];
  const float* bo = (const float*)d_in[8];
  const float* rpb = (const float*)d_in[9];
  short* wsW = (short*)d_ws;
  float* bias_t = (float*)((char*)d_ws + 294912);  // [6][49][49] f32, 57.6 KB

  const int B = in_sizes[0] / (NTOK * CDIM);
  const int nW = in_sizes[2] / (NTOK * NTOK);

  prep_w<<<576, 256, 0, stream>>>(Wq, Wkv, Wo, wsW);
  prep_bias<<<57, 256, 0, stream>>>(rpb, bias_t);
  wmsa_kernel<<<B, 512, 0, stream>>>(q, kv, mask, bq, bkv, bo, wsW, bias_t,
                                     (float*)d_out, nW);
}